// Round 1
// baseline (1394.344 us; speedup 1.0000x reference)
//
#include <hip/hip_runtime.h>

#define BB 128
#define TT 1024
#define VV 192
#define HALF 96
#define NTHREADS 384
#define NWAVES 6

__launch_bounds__(NTHREADS)
__global__ void crf_kernel(const float* __restrict__ emissions,
                           const int* __restrict__ tags,
                           const int* __restrict__ mask,
                           const float* __restrict__ trans,
                           const float* __restrict__ start_trans,
                           const float* __restrict__ end_trans,
                           float* __restrict__ out)
{
    const int b = blockIdx.x;
    const int tid = threadIdx.x;
    const int g = tid / VV;       // i-half: 0 or 1
    const int j = tid - g * VV;   // 0..191
    const int lane = tid & 63;
    const int wid = tid >> 6;

    __shared__ __align__(16) float pbuf[2][VV];
    __shared__ float part[2 * VV];
    __shared__ float wred[NWAVES];
    __shared__ float wg[NWAVES];
    __shared__ int   wsl[NWAVES];
    __shared__ float sh_logden;

    const float* em_b = emissions + (size_t)b * TT * VV;
    const int* mask_b = mask + b * TT;

    // ---- load exp(transitions) half-column into registers ----
    float e[HALF];
    {
        const int i0 = g * HALF;
        #pragma unroll
        for (int i = 0; i < HALF; ++i)
            e[i] = __expf(trans[(i0 + i) * VV + j]);
    }

    // ---- init: alpha0 = start + emissions[:,0,:] ----
    float a0 = start_trans[j] + em_b[j];
    float m0 = a0;
    #pragma unroll
    for (int off = 1; off < 64; off <<= 1)
        m0 = fmaxf(m0, __shfl_xor(m0, off));
    if (lane == 0) wred[wid] = m0;
    __syncthreads();
    float M0 = wred[0];
    #pragma unroll
    for (int w = 1; w < NWAVES; ++w) M0 = fmaxf(M0, wred[w]);
    float carry = M0;                       // uniform across all threads
    if (g == 0) pbuf[0][j] = __expf(a0 - M0);
    __syncthreads();

    // ---- emission/mask software pipeline (depth 2) ----
    float eexp_cur = __expf(em_b[1 * VV + j]);   // exp(emit at t=1)
    float em_n1 = em_b[2 * VV + j];              // raw emit at t=2
    int mk_cur = mask_b[1];
    int mk_n1 = mask_b[2];

    int cur = 0;
    for (int t = 1; t < TT; ++t) {
        // prefetch for t+2 (clamped)
        int tp = (t + 2 < TT) ? (t + 2) : (TT - 1);
        float em_n2 = em_b[(size_t)tp * VV + j];
        int mk_n2 = mask_b[tp];

        // dot: s_partial = sum_{i in half} p[i] * e[i]  (p broadcast from LDS)
        const float4* p4 = (const float4*)(&pbuf[cur][g * HALF]);
        float s0 = 0.f, s1 = 0.f, s2 = 0.f, s3 = 0.f;
        #pragma unroll
        for (int i4 = 0; i4 < HALF / 4; ++i4) {
            float4 pv = p4[i4];
            s0 = fmaf(pv.x, e[4 * i4 + 0], s0);
            s1 = fmaf(pv.y, e[4 * i4 + 1], s1);
            s2 = fmaf(pv.z, e[4 * i4 + 2], s2);
            s3 = fmaf(pv.w, e[4 * i4 + 3], s3);
        }
        part[tid] = (s0 + s1) + (s2 + s3);
        __syncthreads();                                        // B1

        float sfull = part[j] + part[VV + j];
        float q = sfull * eexp_cur;

        // block max of q (both groups hold identical q[j] sets)
        float mm = q;
        #pragma unroll
        for (int off = 1; off < 64; off <<= 1)
            mm = fmaxf(mm, __shfl_xor(mm, off));
        if (lane == 0) wred[wid] = mm;
        __syncthreads();                                        // B2

        float Mq = wred[0];
        #pragma unroll
        for (int w = 1; w < NWAVES; ++w) Mq = fmaxf(Mq, wred[w]);
        float L = __logf(Mq);
        float pn = q * __expf(-L);       // self-consistent normalizer

        if (mk_cur) carry += L;
        if (g == 0) pbuf[cur ^ 1][j] = mk_cur ? pn : pbuf[cur][j];

        // advance pipeline
        eexp_cur = __expf(em_n1);
        em_n1 = em_n2;
        mk_cur = mk_n1;
        mk_n1 = mk_n2;

        __syncthreads();                                        // B3
        cur ^= 1;
    }

    // ---- final lse: logden = carry + log(sum_j p[j]*exp(end[j])) ----
    float v = (g == 0) ? pbuf[cur][j] * __expf(end_trans[j]) : 0.f;
    #pragma unroll
    for (int off = 1; off < 64; off <<= 1)
        v += __shfl_xor(v, off);
    if (lane == 0) wred[wid] = v;
    __syncthreads();
    if (tid == 0) {
        float ssum = 0.f;
        for (int w = 0; w < NWAVES; ++w) ssum += wred[w];
        sh_logden = carry + __logf(ssum + 1e-8f);
    }

    // ---- gold score + seq_len (strided over t) ----
    float gp = 0.f;
    int sl = 0;
    for (int t = tid; t < TT; t += NTHREADS) {
        sl += mask_b[t];
        if (t >= 1) {
            int tg  = tags[b * TT + t];
            int tgp = tags[b * TT + t - 1];
            float term = em_b[(size_t)t * VV + tg] + trans[tgp * VV + tg];
            gp += mask_b[t] ? term : 0.f;
        }
    }
    #pragma unroll
    for (int off = 1; off < 64; off <<= 1) {
        gp += __shfl_xor(gp, off);
        sl += __shfl_xor(sl, off);
    }
    if (lane == 0) { wg[wid] = gp; wsl[wid] = sl; }
    __syncthreads();
    if (tid == 0) {
        float gold = 0.f; int seqs = 0;
        for (int w = 0; w < NWAVES; ++w) { gold += wg[w]; seqs += wsl[w]; }
        int tg0 = tags[b * TT];
        gold += start_trans[tg0] + em_b[tg0];
        int last_idx = seqs - 1;
        int tgl = tags[b * TT + last_idx];
        gold += end_trans[tgl];
        float seqf = fmaxf((float)seqs, 1.0f);
        out[b] = (sh_logden - gold) / seqf;
    }
}

extern "C" void kernel_launch(void* const* d_in, const int* in_sizes, int n_in,
                              void* d_out, int out_size, void* d_ws, size_t ws_size,
                              hipStream_t stream) {
    const float* emissions   = (const float*)d_in[0];
    const int*   tags        = (const int*)d_in[1];
    const int*   mask        = (const int*)d_in[2];
    const float* trans       = (const float*)d_in[3];
    const float* start_trans = (const float*)d_in[4];
    const float* end_trans   = (const float*)d_in[5];
    float* out = (float*)d_out;

    crf_kernel<<<BB, NTHREADS, 0, stream>>>(emissions, tags, mask, trans,
                                            start_trans, end_trans, out);
}

// Round 2
// 788.823 us; speedup vs baseline: 1.7676x; 1.7676x over previous
//
#include <hip/hip_runtime.h>

#define BB 128
#define TT 1024
#define VV 192
#define HALF 96
#define NTHREADS 384
#define NWAVES 6
#define LN2 0.69314718055994530942f

__launch_bounds__(NTHREADS)
__global__ void crf_kernel(const float* __restrict__ emissions,
                           const int* __restrict__ tags,
                           const int* __restrict__ mask,
                           const float* __restrict__ trans,
                           const float* __restrict__ start_trans,
                           const float* __restrict__ end_trans,
                           float* __restrict__ out)
{
    const int b = blockIdx.x;
    const int tid = threadIdx.x;
    const int j = tid >> 1;       // column 0..191 (lane pairs share j)
    const int g = tid & 1;        // i-half: 0 or 1
    const int lane = tid & 63;
    const int wid = tid >> 6;

    // double-buffered Q vector (exp-space alpha, stale-normalized)
    __shared__ __align__(16) float qbuf[2][VV];
    __shared__ float wred[NWAVES];
    __shared__ float wg[NWAVES];
    __shared__ int   wsl[NWAVES];
    __shared__ float sh_logden;

    const float* em_b = emissions + (size_t)b * TT * VV;
    const int* mask_b = mask + b * TT;

    // ---- exp(transitions) half-column in registers: e[i'] = exp(T[g*96+i', j]) ----
    float e[HALF];
    {
        const int i0 = g * HALF;
        #pragma unroll
        for (int i = 0; i < HALF; ++i)
            e[i] = __expf(trans[(i0 + i) * VV + j]);
    }

    // ---- init: Q0[j] = exp(start[j] + em[0,j]), carry = 0 ----
    {
        float a0 = start_trans[j] + em_b[j];
        if (g == 0) qbuf[0][j] = __expf(a0);
    }
    float carry2 = 0.f;   // accumulated log2 normalizers (uniform across threads)
    __syncthreads();

    // ---- emission/mask software pipeline (depth 2) ----
    float eexp_cur = __expf(em_b[1 * VV + j]);   // exp(emit at t=1)
    float em_n1 = em_b[2 * VV + j];              // raw emit at t=2
    int mk_cur = mask_b[1];
    int mk_n1 = mask_b[2];

    int cur = 0;
    for (int t = 1; t < TT; ++t) {
        // prefetch for t+2 (clamped)
        int tp = (t + 2 < TT) ? (t + 2) : (TT - 1);
        float em_n2 = em_b[(size_t)tp * VV + j];
        int mk_n2 = mask_b[tp];

        // issue the two scalar LDS reads early so their latency hides under FMAs
        float q0 = qbuf[cur][0];        // stale normalizer reference (broadcast)
        float qprev_j = qbuf[cur][j];   // own value (for mask=0 passthrough)

        // dot: s = sum_{i in half g} Q[i] * e[i]   (Q broadcast-read from LDS)
        const float4* p4 = (const float4*)(&qbuf[cur][g * HALF]);
        float s0 = 0.f, s1 = 0.f, s2 = 0.f, s3 = 0.f;
        #pragma unroll
        for (int i4 = 0; i4 < HALF / 4; ++i4) {
            float4 pv = p4[i4];
            s0 = fmaf(pv.x, e[4 * i4 + 0], s0);
            s1 = fmaf(pv.y, e[4 * i4 + 1], s1);
            s2 = fmaf(pv.z, e[4 * i4 + 2], s2);
            s3 = fmaf(pv.w, e[4 * i4 + 3], s3);
        }
        float part = (s0 + s1) + (s2 + s3);

        // combine the two i-halves: adjacent lanes hold the same j
        float qfull = part + __shfl_xor(part, 1);

        // stale-normalized update: Qnew = qfull * eexp / (q0 * 256)
        float r = __builtin_amdgcn_rcpf(q0);
        float qnew = qfull * eexp_cur * r * 0.00390625f;

        qnew = mk_cur ? qnew : qprev_j;
        carry2 += mk_cur ? (__log2f(q0) + 8.0f) : 0.f;

        if (g == 0) qbuf[cur ^ 1][j] = qnew;

        // advance pipeline
        eexp_cur = __expf(em_n1);
        em_n1 = em_n2;
        mk_cur = mk_n1;
        mk_n1 = mk_n2;

        __syncthreads();
        cur ^= 1;
    }

    // ---- final lse: logden = ln2*carry2 + log(sum_j Q[j]*exp(end[j])) ----
    float v = (g == 0) ? qbuf[cur][j] * __expf(end_trans[j]) : 0.f;
    #pragma unroll
    for (int off = 1; off < 64; off <<= 1)
        v += __shfl_xor(v, off);
    if (lane == 0) wred[wid] = v;
    __syncthreads();
    if (tid == 0) {
        float ssum = 0.f;
        for (int w = 0; w < NWAVES; ++w) ssum += wred[w];
        sh_logden = LN2 * carry2 + __logf(ssum + 1e-8f);
    }

    // ---- gold score + seq_len (strided over t) ----
    float gp = 0.f;
    int sl = 0;
    for (int t = tid; t < TT; t += NTHREADS) {
        sl += mask_b[t];
        if (t >= 1) {
            int tg  = tags[b * TT + t];
            int tgp = tags[b * TT + t - 1];
            float term = em_b[(size_t)t * VV + tg] + trans[tgp * VV + tg];
            gp += mask_b[t] ? term : 0.f;
        }
    }
    #pragma unroll
    for (int off = 1; off < 64; off <<= 1) {
        gp += __shfl_xor(gp, off);
        sl += __shfl_xor(sl, off);
    }
    if (lane == 0) { wg[wid] = gp; wsl[wid] = sl; }
    __syncthreads();
    if (tid == 0) {
        float gold = 0.f; int seqs = 0;
        for (int w = 0; w < NWAVES; ++w) { gold += wg[w]; seqs += wsl[w]; }
        int tg0 = tags[b * TT];
        gold += start_trans[tg0] + em_b[tg0];
        int last_idx = seqs - 1;
        int tgl = tags[b * TT + last_idx];
        gold += end_trans[tgl];
        float seqf = fmaxf((float)seqs, 1.0f);
        out[b] = (sh_logden - gold) / seqf;
    }
}

extern "C" void kernel_launch(void* const* d_in, const int* in_sizes, int n_in,
                              void* d_out, int out_size, void* d_ws, size_t ws_size,
                              hipStream_t stream) {
    const float* emissions   = (const float*)d_in[0];
    const int*   tags        = (const int*)d_in[1];
    const int*   mask        = (const int*)d_in[2];
    const float* trans       = (const float*)d_in[3];
    const float* start_trans = (const float*)d_in[4];
    const float* end_trans   = (const float*)d_in[5];
    float* out = (float*)d_out;

    crf_kernel<<<BB, NTHREADS, 0, stream>>>(emissions, tags, mask, trans,
                                            start_trans, end_trans, out);
}